// Round 3
// baseline (292.344 us; speedup 1.0000x reference)
//
#include <hip/hip_runtime.h>
#include <math.h>

#define DIM 128

typedef __attribute__((ext_vector_type(8))) short bf16x8;
typedef __attribute__((ext_vector_type(4))) float f32x4;

// RNE float -> bf16 bits
static __device__ __forceinline__ ushort f2bf(float f) {
    unsigned u = __float_as_uint(f);
    u += 0x7FFFu + ((u >> 16) & 1u);
    return (ushort)(u >> 16);
}

// ---------------- Phase 0: exclusive scan of lengths -> offsets ----------------
__global__ __launch_bounds__(1024) void scan_kernel(const int* __restrict__ lengths,
                                                    int* __restrict__ offsets, int batch) {
    __shared__ int tsum[1024];
    int tid = threadIdx.x;
    int per = (batch + 1023) >> 10;
    int start = tid * per;
    int s = 0;
    for (int i = 0; i < per; ++i) {
        int idx = start + i;
        if (idx < batch) s += lengths[idx];
    }
    tsum[tid] = s;
    __syncthreads();
    for (int off = 1; off < 1024; off <<= 1) {
        int v = (tid >= off) ? tsum[tid - off] : 0;
        __syncthreads();
        tsum[tid] += v;
        __syncthreads();
    }
    int base = (tid == 0) ? 0 : tsum[tid - 1];
    for (int i = 0; i < per; ++i) {
        int idx = start + i;
        if (idx < batch) { offsets[idx] = base; base += lengths[idx]; }
    }
}

// ---------------- Phase 1 (fused): per segment, scores + m_b, S'_b, t_b ----------
// Persistent 512 blocks (2/CU). W1^T bf16 B-frags in registers (loaded once via LDS).
// Per segment (len <= 128 rows): stage emb fp32->bf16 swizzled -> MFMA scores -> LDS
// -> wave0 computes m_b and weights exp(s-m_b) -> 8-slice float4 weighted sum
// re-reading the (L2-hot) fp32 rows -> t_b to ws. Emb touches HBM exactly once.
__global__ __launch_bounds__(256, 2) void fused_kernel(
        const float* __restrict__ emb, const float* __restrict__ W1,
        const float* __restrict__ b1, const float* __restrict__ W2,
        const float* __restrict__ b2, const int* __restrict__ offsets,
        const int* __restrict__ lengths, int batch, int T,
        float* __restrict__ mArr, float* __restrict__ sArr,
        float* __restrict__ tvec) {
    __shared__ ushort sA[128 * 128];   // bf16: W1^T during init, then A tiles
    __shared__ float sScore[128];
    __shared__ float sW[128];
    __shared__ float sMS[2];
    __shared__ float sPool[8][128];

    int tid = threadIdx.x;
    int lane = tid & 63;
    int wv = tid >> 6;
    int lr = lane & 15;
    int lg = lane >> 4;

    // ---- stage W1^T (bf16, swizzled)
    for (int i = 0; i < 16; ++i) {
        int q = tid + i * 256;
        int n = q >> 5;
        int k4 = q & 31;
        ushort4 w;
        w.x = f2bf(W1[(k4 * 4 + 0) * DIM + n]);
        w.y = f2bf(W1[(k4 * 4 + 1) * DIM + n]);
        w.z = f2bf(W1[(k4 * 4 + 2) * DIM + n]);
        w.w = f2bf(W1[(k4 * 4 + 3) * DIM + n]);
        int c = k4 >> 1;
        int a16 = n * 128 + ((c ^ (n & 7)) * 8) + (k4 & 1) * 4;
        *(ushort4*)&sA[a16] = w;
    }
    __syncthreads();

    bf16x8 bfrag[8][4];
    #pragma unroll
    for (int ct = 0; ct < 8; ++ct) {
        int n = ct * 16 + lr;
        #pragma unroll
        for (int kc = 0; kc < 4; ++kc) {
            int c = lg + kc * 4;
            bfrag[ct][kc] = *(const bf16x8*)&sA[n * 128 + ((c ^ (n & 7)) * 8)];
        }
    }
    float b1reg[8], w2reg[8];
    #pragma unroll
    for (int ct = 0; ct < 8; ++ct) {
        b1reg[ct] = b1[ct * 16 + lr];
        w2reg[ct] = W2[ct * 16 + lr];
    }
    float b2v = b2[0];
    __syncthreads();   // W1^T reads done; sA reusable

    const float4* emb4 = (const float4*)emb;

    for (int seg = blockIdx.x; seg < batch; seg += gridDim.x) {
        int off = offsets[seg];
        int len = lengths[seg];
        if (len > 128) len = 128;          // segment-size cap (data: constant 50)
        int nrt = (len > 64) ? 2 : 1;
        int tileRows = nrt << 6;

        // ---- stage A rows (fp32 -> bf16, swizzled; zero-pad to tileRows)
        int nIter = tileRows >> 3;
        for (int i = 0; i < nIter; ++i) {
            int q = tid + i * 256;
            int r = q >> 5;
            int k4 = q & 31;
            float4 v = make_float4(0.f, 0.f, 0.f, 0.f);
            if (r < len) v = emb4[(long)(off + r) * 32 + k4];
            ushort4 w;
            w.x = f2bf(v.x); w.y = f2bf(v.y); w.z = f2bf(v.z); w.w = f2bf(v.w);
            int c = k4 >> 1;
            int a16 = r * 128 + ((c ^ (r & 7)) * 8) + (k4 & 1) * 4;
            *(ushort4*)&sA[a16] = w;
        }
        __syncthreads();

        // ---- MFMA scores -> sScore
        for (int rt = 0; rt < nrt; ++rt) {
            int rbase = (nrt == 2) ? (wv * 32 + rt * 16) : (wv * 16);
            int r = rbase + lr;
            bf16x8 a[4];
            #pragma unroll
            for (int kc = 0; kc < 4; ++kc) {
                int c = lg + kc * 4;
                a[kc] = *(const bf16x8*)&sA[r * 128 + ((c ^ (r & 7)) * 8)];
            }
            f32x4 acc[8];
            #pragma unroll
            for (int ct = 0; ct < 8; ++ct) acc[ct] = (f32x4)(0.f);
            #pragma unroll
            for (int ct = 0; ct < 8; ++ct)
                #pragma unroll
                for (int kc = 0; kc < 4; ++kc)
                    acc[ct] = __builtin_amdgcn_mfma_f32_16x16x32_bf16(a[kc], bfrag[ct][kc], acc[ct], 0, 0, 0);
            #pragma unroll
            for (int reg = 0; reg < 4; ++reg) {
                float s = 0.f;
                #pragma unroll
                for (int ct = 0; ct < 8; ++ct) {
                    float h = acc[ct][reg] + b1reg[ct];
                    h = fmaxf(h, 0.f);
                    s = fmaf(h, w2reg[ct], s);
                }
                s += __shfl_xor(s, 1, 64);
                s += __shfl_xor(s, 2, 64);
                s += __shfl_xor(s, 4, 64);
                s += __shfl_xor(s, 8, 64);
                if (lr == 0) sScore[rbase + lg * 4 + reg] = s + b2v;
            }
        }
        __syncthreads();

        // ---- wave 0: m_b, weights, S'_b
        if (tid < 64) {
            float v0 = (tid < len) ? sScore[tid] : -INFINITY;
            float v1 = (tid + 64 < len) ? sScore[tid + 64] : -INFINITY;
            float m = fmaxf(v0, v1);
            #pragma unroll
            for (int o = 1; o < 64; o <<= 1) m = fmaxf(m, __shfl_xor(m, o, 64));
            float e0 = expf(v0 - m);
            float e1 = expf(v1 - m);
            sW[tid] = e0;
            sW[tid + 64] = e1;
            float s = e0 + e1;
            #pragma unroll
            for (int o = 1; o < 64; o <<= 1) s += __shfl_xor(s, o, 64);
            if (tid == 0) { sMS[0] = m; sMS[1] = (len > 0) ? s : 0.f; }
        }
        __syncthreads();

        // ---- weighted sum: 8 row-slices x 32 d-groups of float4 (emb fp32, L2-hot)
        int slice = tid >> 5;
        int dg4 = tid & 31;                 // float4 index within row
        float4 acc4 = make_float4(0.f, 0.f, 0.f, 0.f);
        #pragma unroll 4
        for (int r = slice; r < len; r += 8) {
            float w = sW[r];
            float4 e = emb4[(long)(off + r) * 32 + dg4];
            acc4.x = fmaf(w, e.x, acc4.x);
            acc4.y = fmaf(w, e.y, acc4.y);
            acc4.z = fmaf(w, e.z, acc4.z);
            acc4.w = fmaf(w, e.w, acc4.w);
        }
        *(float4*)&sPool[slice][dg4 * 4] = acc4;
        __syncthreads();

        if (tid < 128) {
            float s = 0.f;
            #pragma unroll
            for (int k = 0; k < 8; ++k) s += sPool[k][tid];
            tvec[(long)seg * DIM + tid] = s;
        }
        if (tid == 0) { mArr[seg] = sMS[0]; sArr[seg] = sMS[1]; }
        // no extra barrier needed: next iter's LDS writes are fenced by its own syncs
        __syncthreads();
    }
}

// ---------------- Phase 2: global M, 1/S from per-segment (m_b, S'_b) ----------
__global__ __launch_bounds__(1024) void segreduce_kernel(const float* __restrict__ mArr,
        const float* __restrict__ sArr, int batch, float* __restrict__ stats) {
    __shared__ float redm[16], reds[16];
    int tid = threadIdx.x;
    int wave = tid >> 6, ln = tid & 63;
    float m = -INFINITY;
    for (int i = tid; i < batch; i += 1024) m = fmaxf(m, mArr[i]);
    #pragma unroll
    for (int o = 32; o >= 1; o >>= 1) m = fmaxf(m, __shfl_xor(m, o, 64));
    if (ln == 0) redm[wave] = m;
    __syncthreads();
    float M = -INFINITY;
    #pragma unroll
    for (int k = 0; k < 16; ++k) M = fmaxf(M, redm[k]);
    float s = 0.f;
    for (int i = tid; i < batch; i += 1024) s += sArr[i] * expf(mArr[i] - M);
    #pragma unroll
    for (int o = 32; o >= 1; o >>= 1) s += __shfl_xor(s, o, 64);
    if (ln == 0) reds[wave] = s;
    __syncthreads();
    if (tid == 0) {
        float S = 0.f;
        #pragma unroll
        for (int k = 0; k < 16; ++k) S += reds[k];
        stats[0] = M;
        stats[1] = 1.0f / S;
    }
}

// ---------------- Phase 3: out[b][d] = t_b[d] * exp(m_b - M) / S ----------------
__global__ __launch_bounds__(256) void scale_kernel(const float* __restrict__ tvec,
        const float* __restrict__ mArr, const float* __restrict__ stats,
        float* __restrict__ out, int n) {
    int idx = blockIdx.x * 256 + threadIdx.x;
    if (idx >= n) return;
    float M = stats[0], invS = stats[1];
    int b = idx >> 7;
    out[idx] = tvec[idx] * (expf(mArr[b] - M) * invS);
}

extern "C" void kernel_launch(void* const* d_in, const int* in_sizes, int n_in,
                              void* d_out, int out_size, void* d_ws, size_t ws_size,
                              hipStream_t stream) {
    const float* emb     = (const float*)d_in[0];
    const float* W1      = (const float*)d_in[1];
    const float* b1      = (const float*)d_in[2];
    const float* W2      = (const float*)d_in[3];
    const float* b2      = (const float*)d_in[4];
    const int*   lengths = (const int*)d_in[5];
    int T = in_sizes[0] / DIM;
    int batch = in_sizes[5];
    float* out = (float*)d_out;

    // ws: offsets[batch] | mArr[batch] | sArr[batch] | stats[2] | tvec[batch*DIM]
    int*   offsets = (int*)d_ws;
    float* mArr    = (float*)(offsets + batch);
    float* sArr    = mArr + batch;
    float* stats   = sArr + batch;
    float* tvec    = stats + 2;

    scan_kernel<<<1, 1024, 0, stream>>>(lengths, offsets, batch);
    fused_kernel<<<512, 256, 0, stream>>>(emb, W1, b1, W2, b2, offsets, lengths,
                                          batch, T, mArr, sArr, tvec);
    segreduce_kernel<<<1, 1024, 0, stream>>>(mArr, sArr, batch, stats);
    scale_kernel<<<(out_size + 255) / 256, 256, 0, stream>>>(tvec, mArr, stats, out, out_size);
}

// Round 4
// 254.625 us; speedup vs baseline: 1.1481x; 1.1481x over previous
//
#include <hip/hip_runtime.h>
#include <hip/hip_bf16.h>
#include <math.h>

#define DIM 128

typedef __attribute__((ext_vector_type(8))) short bf16x8;
typedef __attribute__((ext_vector_type(4))) float f32x4;

union FragU { bf16x8 v; __hip_bfloat162 h[4]; };

// RNE float -> bf16 bits (for W1 staging; verified numerics R2/R3)
static __device__ __forceinline__ ushort f2bf(float f) {
    unsigned u = __float_as_uint(f);
    u += 0x7FFFu + ((u >> 16) & 1u);
    return (ushort)(u >> 16);
}

// ---------------- Phase 0: exclusive scan of lengths -> offsets ----------------
__global__ __launch_bounds__(1024) void scan_kernel(const int* __restrict__ lengths,
                                                    int* __restrict__ offsets, int batch) {
    __shared__ int tsum[1024];
    int tid = threadIdx.x;
    int per = (batch + 1023) >> 10;
    int start = tid * per;
    int s = 0;
    for (int i = 0; i < per; ++i) {
        int idx = start + i;
        if (idx < batch) s += lengths[idx];
    }
    tsum[tid] = s;
    __syncthreads();
    for (int off = 1; off < 1024; off <<= 1) {
        int v = (tid >= off) ? tsum[tid - off] : 0;
        __syncthreads();
        tsum[tid] += v;
        __syncthreads();
    }
    int base = (tid == 0) ? 0 : tsum[tid - 1];
    for (int i = 0; i < per; ++i) {
        int idx = start + i;
        if (idx < batch) { offsets[idx] = base; base += lengths[idx]; }
    }
}

// ---------------- Phase 1 (fused, wave-per-segment, barrier-free) --------------
// W1^T bf16 in LDS (XOR-swizzled), staged once + ONE barrier. After that each
// wave owns segments independently: A-frags global->reg (no LDS staging), MFMA
// scores, in-wave softmax (lane=row), pool via coalesced L2-hot float2 re-reads,
// online-softmax merge across 64-row chunks. 1024 blocks = 4/CU, 16 waves/CU.
__global__ __launch_bounds__(256, 4) void fused_kernel(
        const float* __restrict__ emb, const float* __restrict__ W1,
        const float* __restrict__ b1, const float* __restrict__ W2,
        const float* __restrict__ b2, const int* __restrict__ offsets,
        const int* __restrict__ lengths, int batch,
        float* __restrict__ mArr, float* __restrict__ sArr,
        float* __restrict__ tvec) {
    __shared__ ushort sB[128 * 128];   // W1^T bf16, swizzled: row n (out-col), k

    int tid = threadIdx.x;
    int lane = tid & 63;
    int wv = tid >> 6;
    int lr = lane & 15;
    int lg = lane >> 4;

    // ---- stage W1^T (bf16, swizzled) — once per block
    for (int i = 0; i < 16; ++i) {
        int q = tid + i * 256;
        int n = q >> 5;
        int k4 = q & 31;
        ushort4 w;
        w.x = f2bf(W1[(k4 * 4 + 0) * DIM + n]);
        w.y = f2bf(W1[(k4 * 4 + 1) * DIM + n]);
        w.z = f2bf(W1[(k4 * 4 + 2) * DIM + n]);
        w.w = f2bf(W1[(k4 * 4 + 3) * DIM + n]);
        int c = k4 >> 1;
        int a16 = n * 128 + ((c ^ (n & 7)) * 8) + (k4 & 1) * 4;
        *(ushort4*)&sB[a16] = w;
    }
    // per-lane epilogue constants (col = ct*16 + lr)
    float b1reg[8], w2reg[8];
    #pragma unroll
    for (int ct = 0; ct < 8; ++ct) {
        b1reg[ct] = b1[ct * 16 + lr];
        w2reg[ct] = W2[ct * 16 + lr];
    }
    float b2v = b2[0];
    __syncthreads();   // sB ready; no further barriers

    const float4* emb4 = (const float4*)emb;
    int gwave = blockIdx.x * 4 + wv;
    int nwaves = gridDim.x * 4;

    for (int seg = gwave; seg < batch; seg += nwaves) {
        int off = offsets[seg];
        int len = lengths[seg];
        float m_run = -INFINITY, S_run = 0.f;
        float t0 = 0.f, t1 = 0.f;

        for (int cb = 0; cb < len; cb += 64) {
            int n = len - cb; if (n > 64) n = 64;
            float sv_mine = -INFINITY;

            #pragma unroll
            for (int rt = 0; rt < 4; ++rt) {
                if (rt * 16 >= n) break;
                int r = cb + rt * 16 + lr;          // row within segment
                bool valid = (r < len);
                long rb = (long)(off + r) * 32;     // float4 row base

                bf16x8 a[4];
                #pragma unroll
                for (int kc = 0; kc < 4; ++kc) {
                    float4 u = make_float4(0.f, 0.f, 0.f, 0.f);
                    float4 v2 = make_float4(0.f, 0.f, 0.f, 0.f);
                    if (valid) {
                        u  = emb4[rb + kc * 8 + lg * 2];
                        v2 = emb4[rb + kc * 8 + lg * 2 + 1];
                    }
                    FragU f;
                    f.h[0] = __float22bfloat162_rn(make_float2(u.x, u.y));
                    f.h[1] = __float22bfloat162_rn(make_float2(u.z, u.w));
                    f.h[2] = __float22bfloat162_rn(make_float2(v2.x, v2.y));
                    f.h[3] = __float22bfloat162_rn(make_float2(v2.z, v2.w));
                    a[kc] = f.v;
                }

                f32x4 acc[8];
                #pragma unroll
                for (int ct = 0; ct < 8; ++ct) acc[ct] = (f32x4)(0.f);
                #pragma unroll
                for (int ct = 0; ct < 8; ++ct) {
                    #pragma unroll
                    for (int kc = 0; kc < 4; ++kc) {
                        const bf16x8 bf = *(const bf16x8*)
                            &sB[(ct * 16 + lr) * 128 + (((lg + 4 * kc) ^ (lr & 7)) * 8)];
                        acc[ct] = __builtin_amdgcn_mfma_f32_16x16x32_bf16(a[kc], bf, acc[ct], 0, 0, 0);
                    }
                }

                // epilogue: bias+relu+W2 dot, reduce over 16 col-lanes
                float p0s, p1s, p2s, p3s;
                {
                    float p[4];
                    #pragma unroll
                    for (int reg = 0; reg < 4; ++reg) {
                        float s = 0.f;
                        #pragma unroll
                        for (int ct = 0; ct < 8; ++ct) {
                            float h = acc[ct][reg] + b1reg[ct];
                            h = fmaxf(h, 0.f);
                            s = fmaf(h, w2reg[ct], s);
                        }
                        p[reg] = s;
                    }
                    #pragma unroll
                    for (int m = 1; m < 16; m <<= 1) {
                        #pragma unroll
                        for (int reg = 0; reg < 4; ++reg)
                            p[reg] += __shfl_xor(p[reg], m, 64);
                    }
                    p0s = p[0]; p1s = p[1]; p2s = p[2]; p3s = p[3];
                }
                // redistribute: lane l gets rowsum of row (l&15) of this tile
                int r3 = lane & 3;
                float pr = p0s;
                pr = (r3 == 1) ? p1s : pr;
                pr = (r3 == 2) ? p2s : pr;
                pr = (r3 == 3) ? p3s : pr;
                int src = ((lane & 12) << 2) + r3;   // 16*((l&15)>>2) + (l&3)
                float sv = __shfl(pr, src, 64);
                if ((lane >> 4) == rt) sv_mine = sv;
            }

            // lane l holds score of row cb+l (l < n)
            float s_l = (lane < n) ? (sv_mine + b2v) : -INFINITY;
            float m_c = s_l;
            #pragma unroll
            for (int o = 1; o < 64; o <<= 1) m_c = fmaxf(m_c, __shfl_xor(m_c, o, 64));
            float w_l = expf(s_l - m_c);             // 0 for invalid lanes
            float S_c = w_l;
            #pragma unroll
            for (int o = 1; o < 64; o <<= 1) S_c += __shfl_xor(S_c, o, 64);

            // pool chunk: lane l accumulates d = 2l, 2l+1 (coalesced; rows L2/L3-hot)
            float p0 = 0.f, p1 = 0.f;
            const float* rowp = emb + (long)(off + cb) * DIM + 2 * lane;
            #pragma unroll 4
            for (int r2 = 0; r2 < n; ++r2) {
                float wr = __uint_as_float(__builtin_amdgcn_readlane(__float_as_uint(w_l), r2));
                float2 e = *(const float2*)(rowp + (long)r2 * DIM);
                p0 = fmaf(wr, e.x, p0);
                p1 = fmaf(wr, e.y, p1);
            }

            // online merge
            float mn = fmaxf(m_run, m_c);
            float ea = expf(m_run - mn), eb = expf(m_c - mn);
            t0 = t0 * ea + p0 * eb;
            t1 = t1 * ea + p1 * eb;
            S_run = S_run * ea + S_c * eb;
            m_run = mn;
        }

        if (lane == 0) { mArr[seg] = m_run; sArr[seg] = S_run; }
        *(float2*)&tvec[(long)seg * DIM + 2 * lane] = make_float2(t0, t1);
    }
}

// ---------------- Phase 2: global M, 1/S from per-segment (m_b, S'_b) ----------
__global__ __launch_bounds__(1024) void segreduce_kernel(const float* __restrict__ mArr,
        const float* __restrict__ sArr, int batch, float* __restrict__ stats) {
    __shared__ float redm[16], reds[16];
    int tid = threadIdx.x;
    int wave = tid >> 6, ln = tid & 63;
    float m = -INFINITY;
    for (int i = tid; i < batch; i += 1024) m = fmaxf(m, mArr[i]);
    #pragma unroll
    for (int o = 32; o >= 1; o >>= 1) m = fmaxf(m, __shfl_xor(m, o, 64));
    if (ln == 0) redm[wave] = m;
    __syncthreads();
    float M = -INFINITY;
    #pragma unroll
    for (int k = 0; k < 16; ++k) M = fmaxf(M, redm[k]);
    float s = 0.f;
    for (int i = tid; i < batch; i += 1024) s += sArr[i] * expf(mArr[i] - M);
    #pragma unroll
    for (int o = 32; o >= 1; o >>= 1) s += __shfl_xor(s, o, 64);
    if (ln == 0) reds[wave] = s;
    __syncthreads();
    if (tid == 0) {
        float S = 0.f;
        #pragma unroll
        for (int k = 0; k < 16; ++k) S += reds[k];
        stats[0] = M;
        stats[1] = 1.0f / S;
    }
}

// ---------------- Phase 3: out[b][d] = t_b[d] * exp(m_b - M) / S ----------------
__global__ __launch_bounds__(256) void scale_kernel(const float* __restrict__ tvec,
        const float* __restrict__ mArr, const float* __restrict__ stats,
        float* __restrict__ out, int n) {
    int idx = blockIdx.x * 256 + threadIdx.x;
    if (idx >= n) return;
    float M = stats[0], invS = stats[1];
    int b = idx >> 7;
    out[idx] = tvec[idx] * (expf(mArr[b] - M) * invS);
}

extern "C" void kernel_launch(void* const* d_in, const int* in_sizes, int n_in,
                              void* d_out, int out_size, void* d_ws, size_t ws_size,
                              hipStream_t stream) {
    const float* emb     = (const float*)d_in[0];
    const float* W1      = (const float*)d_in[1];
    const float* b1      = (const float*)d_in[2];
    const float* W2      = (const float*)d_in[3];
    const float* b2      = (const float*)d_in[4];
    const int*   lengths = (const int*)d_in[5];
    int batch = in_sizes[5];
    float* out = (float*)d_out;

    // ws: offsets[batch] | mArr[batch] | sArr[batch] | stats[2] | tvec[batch*DIM]
    int*   offsets = (int*)d_ws;
    float* mArr    = (float*)(offsets + batch);
    float* sArr    = mArr + batch;
    float* stats   = sArr + batch;
    float* tvec    = stats + 2;

    scan_kernel<<<1, 1024, 0, stream>>>(lengths, offsets, batch);
    fused_kernel<<<1024, 256, 0, stream>>>(emb, W1, b1, W2, b2, offsets, lengths,
                                           batch, mArr, sArr, tvec);
    segreduce_kernel<<<1, 1024, 0, stream>>>(mArr, sArr, batch, stats);
    scale_kernel<<<(out_size + 255) / 256, 256, 0, stream>>>(tvec, mArr, stats, out, out_size);
}

// Round 5
// 166.116 us; speedup vs baseline: 1.7599x; 1.5328x over previous
//
#include <hip/hip_runtime.h>
#include <hip/hip_bf16.h>
#include <math.h>

#define DIM 128

typedef __attribute__((ext_vector_type(8))) short bf16x8;
typedef __attribute__((ext_vector_type(4))) float f32x4;

union FragU { bf16x8 v; __hip_bfloat162 h[4]; };

// RNE float -> bf16 bits
static __device__ __forceinline__ ushort f2bf(float f) {
    unsigned u = __float_as_uint(f);
    u += 0x7FFFu + ((u >> 16) & 1u);
    return (ushort)(u >> 16);
}

// async global -> LDS, 16B per lane (lds dest wave-uniform base + lane*16)
typedef __attribute__((address_space(1))) const unsigned GASp;
typedef __attribute__((address_space(3))) unsigned LASp;
static __device__ __forceinline__ void gll16(const void* g, void* l) {
    __builtin_amdgcn_global_load_lds((GASp*)g, (LASp*)l, 16, 0, 0);
}

// stage 16 rows x 128 f32 (8KB) into wave-private buf, source pre-swizzled so
// that LDS slot (r, x) holds emb chunk (r, x ^ (r&7))  [16B chunks, 32/row]
static __device__ __forceinline__ void stage16(float* buf, const float* emb,
                                               long row0, long Tm1, int lane) {
    #pragma unroll
    for (int i = 0; i < 8; ++i) {
        int s = i * 64 + lane;
        int r = s >> 5, x = s & 31;
        long gr = row0 + r; gr = (gr > Tm1) ? Tm1 : gr;
        gll16(emb + gr * 128 + ((x ^ (r & 7)) << 2), (char*)buf + i * 1024);
    }
}

// ---------------- Phase 0: exclusive scan of lengths -> offsets ----------------
__global__ __launch_bounds__(1024) void scan_kernel(const int* __restrict__ lengths,
                                                    int* __restrict__ offsets, int batch) {
    __shared__ int tsum[1024];
    int tid = threadIdx.x;
    int per = (batch + 1023) >> 10;
    int start = tid * per;
    int s = 0;
    for (int i = 0; i < per; ++i) {
        int idx = start + i;
        if (idx < batch) s += lengths[idx];
    }
    tsum[tid] = s;
    __syncthreads();
    for (int off = 1; off < 1024; off <<= 1) {
        int v = (tid >= off) ? tsum[tid - off] : 0;
        __syncthreads();
        tsum[tid] += v;
        __syncthreads();
    }
    int base = (tid == 0) ? 0 : tsum[tid - 1];
    for (int i = 0; i < per; ++i) {
        int idx = start + i;
        if (idx < batch) { offsets[idx] = base; base += lengths[idx]; }
    }
}

// ---------------- Phase 1 (fused, wave-per-segment, async-pipelined) -----------
// Per wave: two 8KB LDS half-buffers; 16-row chunks staged via global_load_lds
// (counted vmcnt, loads in flight across compute). Same LDS bytes feed MFMA
// (cvt->bf16 frags) and fp32 online-softmax pooling. B-frags (W1^T bf16) live
// in registers. No barriers after init.
__global__ __launch_bounds__(256, 2) void fused_kernel(
        const float* __restrict__ emb, const float* __restrict__ W1,
        const float* __restrict__ b1, const float* __restrict__ W2,
        const float* __restrict__ b2, const int* __restrict__ offsets,
        const int* __restrict__ lengths, int batch, int T,
        float* __restrict__ mArr, float* __restrict__ sArr,
        float* __restrict__ tvec) {
    __shared__ __align__(16) char smem[65536];

    int tid = threadIdx.x;
    int lane = tid & 63;
    int wv = tid >> 6;
    int lr = lane & 15;
    int lg = lane >> 4;

    // ---- init: stage W1^T (bf16, swizzled) into smem, load B-frags to regs
    ushort* sB = (ushort*)smem;
    for (int i = 0; i < 16; ++i) {
        int q = tid + i * 256;
        int n = q >> 5;
        int k4 = q & 31;
        ushort4 w;
        w.x = f2bf(W1[(k4 * 4 + 0) * DIM + n]);
        w.y = f2bf(W1[(k4 * 4 + 1) * DIM + n]);
        w.z = f2bf(W1[(k4 * 4 + 2) * DIM + n]);
        w.w = f2bf(W1[(k4 * 4 + 3) * DIM + n]);
        int c = k4 >> 1;
        int a16 = n * 128 + ((c ^ (n & 7)) * 8) + (k4 & 1) * 4;
        *(ushort4*)&sB[a16] = w;
    }
    __syncthreads();
    bf16x8 bfrag[8][4];
    #pragma unroll
    for (int ct = 0; ct < 8; ++ct) {
        int n = ct * 16 + lr;
        #pragma unroll
        for (int kc = 0; kc < 4; ++kc) {
            int c = lg + kc * 4;
            bfrag[ct][kc] = *(const bf16x8*)&sB[n * 128 + ((c ^ (n & 7)) * 8)];
        }
    }
    float b1reg[8], w2reg[8];
    #pragma unroll
    for (int ct = 0; ct < 8; ++ct) {
        b1reg[ct] = b1[ct * 16 + lr];
        w2reg[ct] = W2[ct * 16 + lr];
    }
    float b2v = b2[0];
    __syncthreads();   // all B-frag reads done; smem now wave-private buffers

    float* buf0 = (float*)(smem + wv * 16384);
    float* buf1 = (float*)(smem + wv * 16384 + 8192);

    long Tm1 = (long)T - 1;
    int nwaves = gridDim.x * 4;
    int gwave = blockIdx.x * 4 + wv;
    int per = (batch + nwaves - 1) / nwaves;
    int seg0 = gwave * per;
    int seg1 = seg0 + per; if (seg1 > batch) seg1 = batch;

    for (int seg = seg0; seg < seg1; ++seg) {
        long off = offsets[seg];
        int len = lengths[seg];
        int nch = (len + 15) >> 4;
        float m_run = -INFINITY, S_run = 0.f, t0 = 0.f, t1 = 0.f;

        if (nch > 0) stage16(buf0, emb, off, Tm1, lane);
        if (nch > 1) stage16(buf1, emb, off + 16, Tm1, lane);

        for (int c = 0; c < nch; ++c) {
            float* bufc = (c & 1) ? buf1 : buf0;
            if (c + 1 < nch) asm volatile("s_waitcnt vmcnt(8)" ::: "memory");
            else             asm volatile("s_waitcnt vmcnt(0)" ::: "memory");

            // ---- A-frags: swizzled ds_read_b128 pairs + cvt to bf16
            bf16x8 a[4];
            #pragma unroll
            for (int kc = 0; kc < 4; ++kc) {
                int c0 = kc * 8 + lg * 2;
                float4 q0 = *(const float4*)&bufc[(lr * 32 + (c0 ^ (lr & 7))) * 4];
                float4 q1 = *(const float4*)&bufc[(lr * 32 + ((c0 + 1) ^ (lr & 7))) * 4];
                FragU f;
                f.h[0] = __float22bfloat162_rn(make_float2(q0.x, q0.y));
                f.h[1] = __float22bfloat162_rn(make_float2(q0.z, q0.w));
                f.h[2] = __float22bfloat162_rn(make_float2(q1.x, q1.y));
                f.h[3] = __float22bfloat162_rn(make_float2(q1.z, q1.w));
                a[kc] = f.v;
            }

            // ---- MFMA: scores for these 16 rows (C: col=lane&15, row=lg*4+reg)
            f32x4 acc[8];
            #pragma unroll
            for (int ct = 0; ct < 8; ++ct) acc[ct] = (f32x4)(0.f);
            #pragma unroll
            for (int ct = 0; ct < 8; ++ct)
                #pragma unroll
                for (int kc = 0; kc < 4; ++kc)
                    acc[ct] = __builtin_amdgcn_mfma_f32_16x16x32_bf16(a[kc], bfrag[ct][kc], acc[ct], 0, 0, 0);

            // ---- epilogue: rowsum of relu(acc+b1)*W2 over 16 col-lanes
            float p[4];
            #pragma unroll
            for (int reg = 0; reg < 4; ++reg) {
                float s = 0.f;
                #pragma unroll
                for (int ct = 0; ct < 8; ++ct) {
                    float h = acc[ct][reg] + b1reg[ct];
                    h = fmaxf(h, 0.f);
                    s = fmaf(h, w2reg[ct], s);
                }
                p[reg] = s;
            }
            #pragma unroll
            for (int m = 1; m < 16; m <<= 1) {
                #pragma unroll
                for (int reg = 0; reg < 4; ++reg)
                    p[reg] += __shfl_xor(p[reg], m, 64);
            }
            // redistribute: lane l gets score of row (l&15)
            int r3 = lane & 3;
            float pr = p[0];
            pr = (r3 == 1) ? p[1] : pr;
            pr = (r3 == 2) ? p[2] : pr;
            pr = (r3 == 3) ? p[3] : pr;
            int src = ((lane & 12) << 2) + r3;
            float sv = __shfl(pr, src, 64);

            // ---- online softmax merge for this chunk
            int cv = len - c * 16;                     // valid rows (1..16)
            float s_l = (lr < cv) ? (sv + b2v) : -INFINITY;
            float m_c = s_l;
            #pragma unroll
            for (int o = 1; o < 16; o <<= 1) m_c = fmaxf(m_c, __shfl_xor(m_c, o, 64));
            float m_new = fmaxf(m_run, m_c);
            float ea = expf(m_run - m_new);            // 0 on first chunk
            float w_l = expf(s_l - m_new);             // 0 for invalid rows
            float S_c = w_l;
            #pragma unroll
            for (int o = 1; o < 16; o <<= 1) S_c += __shfl_xor(S_c, o, 64);
            S_run = S_run * ea + S_c;
            m_run = m_new;

            // ---- pool chunk from LDS fp32 (swizzled b64 reads), d = 2*lane(+1)
            t0 *= ea; t1 *= ea;
            int xc = lane >> 1, xh = lane & 1;
            #pragma unroll
            for (int j = 0; j < 16; ++j) {
                float wj = __uint_as_float(__builtin_amdgcn_readlane(__float_as_uint(w_l), j));
                float2 e = *(const float2*)&bufc[(j * 32 + (xc ^ (j & 7))) * 4 + xh * 2];
                t0 = fmaf(wj, e.x, t0);
                t1 = fmaf(wj, e.y, t1);
            }

            // ---- prefetch chunk c+2 into bufc (its ds_reads are all consumed)
            asm volatile("s_waitcnt lgkmcnt(0)" ::: "memory");
            if (c + 2 < nch) stage16(bufc, emb, off + (long)(c + 2) * 16, Tm1, lane);
        }

        *(float2*)&tvec[(long)seg * DIM + 2 * lane] = make_float2(t0, t1);
        if (lane == 0) { mArr[seg] = m_run; sArr[seg] = S_run; }
    }
}

// ---------------- Phase 2: global M, 1/S from per-segment (m_b, S'_b) ----------
__global__ __launch_bounds__(1024) void segreduce_kernel(const float* __restrict__ mArr,
        const float* __restrict__ sArr, int batch, float* __restrict__ stats) {
    __shared__ float redm[16], reds[16];
    int tid = threadIdx.x;
    int wave = tid >> 6, ln = tid & 63;
    float m = -INFINITY;
    for (int i = tid; i < batch; i += 1024) m = fmaxf(m, mArr[i]);
    #pragma unroll
    for (int o = 32; o >= 1; o >>= 1) m = fmaxf(m, __shfl_xor(m, o, 64));
    if (ln == 0) redm[wave] = m;
    __syncthreads();
    float M = -INFINITY;
    #pragma unroll
    for (int k = 0; k < 16; ++k) M = fmaxf(M, redm[k]);
    float s = 0.f;
    for (int i = tid; i < batch; i += 1024) s += sArr[i] * expf(mArr[i] - M);
    #pragma unroll
    for (int o = 32; o >= 1; o >>= 1) s += __shfl_xor(s, o, 64);
    if (ln == 0) reds[wave] = s;
    __syncthreads();
    if (tid == 0) {
        float S = 0.f;
        #pragma unroll
        for (int k = 0; k < 16; ++k) S += reds[k];
        stats[0] = M;
        stats[1] = 1.0f / S;
    }
}

// ---------------- Phase 3: out[b][d] = t_b[d] * exp(m_b - M) / S ----------------
__global__ __launch_bounds__(256) void scale_kernel(const float* __restrict__ tvec,
        const float* __restrict__ mArr, const float* __restrict__ stats,
        float* __restrict__ out, int n) {
    int idx = blockIdx.x * 256 + threadIdx.x;
    if (idx >= n) return;
    float M = stats[0], invS = stats[1];
    int b = idx >> 7;
    out[idx] = tvec[idx] * (expf(mArr[b] - M) * invS);
}

extern "C" void kernel_launch(void* const* d_in, const int* in_sizes, int n_in,
                              void* d_out, int out_size, void* d_ws, size_t ws_size,
                              hipStream_t stream) {
    const float* emb     = (const float*)d_in[0];
    const float* W1      = (const float*)d_in[1];
    const float* b1      = (const float*)d_in[2];
    const float* W2      = (const float*)d_in[3];
    const float* b2      = (const float*)d_in[4];
    const int*   lengths = (const int*)d_in[5];
    int T = in_sizes[0] / DIM;
    int batch = in_sizes[5];
    float* out = (float*)d_out;

    // ws: offsets[batch] | mArr[batch] | sArr[batch] | stats[2] | tvec[batch*DIM]
    int*   offsets = (int*)d_ws;
    float* mArr    = (float*)(offsets + batch);
    float* sArr    = mArr + batch;
    float* stats   = sArr + batch;
    float* tvec    = stats + 2;

    scan_kernel<<<1, 1024, 0, stream>>>(lengths, offsets, batch);
    fused_kernel<<<512, 256, 0, stream>>>(emb, W1, b1, W2, b2, offsets, lengths,
                                          batch, T, mArr, sArr, tvec);
    segreduce_kernel<<<1, 1024, 0, stream>>>(mArr, sArr, batch, stats);
    scale_kernel<<<(out_size + 255) / 256, 256, 0, stream>>>(tvec, mArr, stats, out, out_size);
}